// Round 1
// baseline (402.391 us; speedup 1.0000x reference)
//
#include <hip/hip_runtime.h>

#define GN      512
#define GNN     (GN * GN)
#define TILE    32
#define HALO    16          // halo radius = max steps per chunk
#define LSTR    68          // LDS row stride in floats (68*4=272 B, 16B-aligned, non-pow2)
#define LROWS   66          // 1 pad row + 64 region rows + 1 pad row
#define NTHR    1024

// Temporal-blocked chunk with register-resident cells.
// Each thread owns 4 consecutive cells (one float4) of the 64x64 region:
// u_cur, u_prev, K*c^2, boundary mask all in registers. LDS holds only the
// neighbor-exchange surface (double-buffered). Trapezoid invariant: after s
// steps, cells within distance >= s of the region edge are exact; the 32x32
// output tile is at distance >= 16, and nsteps <= 16.
//
// Key change vs previous version: the step loop uses a RAW s_barrier with a
// manual lgkmcnt(0)-only wait. __syncthreads() would emit
// s_waitcnt vmcnt(0) expcnt(0) lgkmcnt(0) before s_barrier, forcing the
// per-step global output store to drain to L2/HBM inside the critical path
// of every one of the 256 steps (~1 MB/step serialized). The stores are only
// consumed by the NEXT kernel launch, so they may float across barriers;
// only LDS ordering (lgkmcnt) is required for the ping-pong buffers.
__global__ __launch_bounds__(NTHR)
void wave_chunk(const float* __restrict__ ucur,   // u at chunk base
                const float* __restrict__ uprev,  // u at chunk base - 1
                const float* __restrict__ alpha,
                float* __restrict__ out,
                int slice0, int nsteps)
{
    __shared__ __align__(16) float bufA[LROWS * LSTR];
    __shared__ __align__(16) float bufB[LROWS * LSTR];

    const int tid = threadIdx.x;
    const int r   = tid >> 4;        // region row 0..63
    const int c   = tid & 15;        // 4-cell group 0..15
    const int jc  = c << 2;          // region col of first owned cell

    const int bx  = blockIdx.x & 15;
    const int by  = blockIdx.x >> 4;
    const int ti0 = by * TILE, tj0 = bx * TILE;
    const int gi  = ti0 - HALO + r;      // global row of my cells
    const int gj0 = tj0 - HALO + jc;     // global col of first cell (mult of 4)

    // zero whole LDS (pad rows/cols must read as finite zeros)
    for (int k = tid; k < LROWS * LSTR; k += NTHR) { bufA[k] = 0.0f; bufB[k] = 0.0f; }

    const float DX = 10.0f / 511.0f;
    const float K  = (5e-5f * 5e-5f) / (DX * DX);   // DT2/DX2

    // ---- K*c^2 for my 4 cells (registers) ----
    float amp[4], cxs[4], cys[4];
#pragma unroll
    for (int g = 0; g < 4; ++g) {
        amp[g] = alpha[g];
        cxs[g] = alpha[4 + g];
        cys[g] = alpha[8 + g];
    }
    const float X = -5.0f + (float)gi * DX;
    float4 kc2;
    {
        float cm[4];
#pragma unroll
        for (int m = 0; m < 4; ++m) {
            const float Y = -5.0f + (float)(gj0 + m) * DX;
            float cv = 2.0f;
#pragma unroll
            for (int g = 0; g < 4; ++g) {
                const float dx = X - cxs[g], dy = Y - cys[g];
                cv += amp[g] * __expf(-(dx * dx + dy * dy));
            }
            cm[m] = K * (cv * cv);       // same association as before: (K*c2)*S
        }
        kc2 = make_float4(cm[0], cm[1], cm[2], cm[3]);
    }

    // ---- interior mask (registers); boundary & out-of-domain cells pinned to 0 ----
    const bool rin = (gi >= 1) && (gi <= GN - 2);
    float4 bm;
    bm.x = (rin && gj0 + 0 >= 1 && gj0 + 0 <= GN - 2) ? 1.0f : 0.0f;
    bm.y = (rin && gj0 + 1 >= 1 && gj0 + 1 <= GN - 2) ? 1.0f : 0.0f;
    bm.z = (rin && gj0 + 2 >= 1 && gj0 + 2 <= GN - 2) ? 1.0f : 0.0f;
    bm.w = (rin && gj0 + 3 >= 1 && gj0 + 3 <= GN - 2) ? 1.0f : 0.0f;

    // ---- load my cells (domain width 512 and gj0 % 4 == 0 -> group fully in or out)
    float4 cur4 = make_float4(0.f, 0.f, 0.f, 0.f);
    float4 prv4 = cur4;
    const bool rowin = ((unsigned)gi < GN);
    const bool colin = ((unsigned)gj0 <= (GN - 4));
    if (rowin && colin) {
        const size_t g = (size_t)gi * GN + gj0;
        cur4 = *reinterpret_cast<const float4*>(ucur + g);
        prv4 = *reinterpret_cast<const float4*>(uprev + g);
    }

    const int idx = (r + 1) * LSTR + jc;     // my slot in the exchange surface
    *reinterpret_cast<float4*>(bufA + idx) = cur4;
    __syncthreads();   // once per kernel: full sync after init is fine

    const bool inTile = (r >= HALO) && (r < HALO + TILE) &&
                        (jc >= HALO) && (jc < HALO + TILE);
    // Output pointer, strength-reduced: advance by one slice per step.
    // (Wild for non-inTile threads; never dereferenced there.)
    float* op = out + (size_t)slice0 * GNN + (size_t)gi * GN + gj0;

    float* A = bufA;
    float* B = bufB;
    for (int s = 0; s < nsteps; ++s) {
        const float4 up = *reinterpret_cast<const float4*>(A + idx - LSTR);
        const float4 dn = *reinterpret_cast<const float4*>(A + idx + LSTR);
        const float  lf = A[idx - 1];
        const float  rt = A[idx + 4];

        float4 nw;
        nw.x = bm.x * (2.0f * cur4.x - prv4.x + kc2.x * (up.x + dn.x + lf     + cur4.y - 4.0f * cur4.x));
        nw.y = bm.y * (2.0f * cur4.y - prv4.y + kc2.y * (up.y + dn.y + cur4.x + cur4.z - 4.0f * cur4.y));
        nw.z = bm.z * (2.0f * cur4.z - prv4.z + kc2.z * (up.z + dn.z + cur4.y + cur4.w - 4.0f * cur4.z));
        nw.w = bm.w * (2.0f * cur4.w - prv4.w + kc2.w * (up.w + dn.w + cur4.z + rt     - 4.0f * cur4.w));

        *reinterpret_cast<float4*>(B + idx) = nw;
        prv4 = cur4;
        cur4 = nw;

        if (inTile) {   // my 4 cells are part of the exact 32x32 tile: store from regs
            *reinterpret_cast<float4*>(op) = nw;
        }
        op += GNN;

        // LDS-only ordered barrier: wait for my ds_write (and my reads of the
        // buffer about to be overwritten) but let global stores stay in flight.
        asm volatile("s_waitcnt lgkmcnt(0)" ::: "memory");
        __builtin_amdgcn_s_barrier();

        float* t = A; A = B; B = t;
    }
}

extern "C" void kernel_launch(void* const* d_in, const int* in_sizes, int n_in,
                              void* d_out, int out_size, void* d_ws, size_t ws_size,
                              hipStream_t stream)
{
    const float* u0    = (const float*)d_in[0];
    const float* alpha = (const float*)d_in[1];
    float*       out   = (float*)d_out;

    // 15 chunks x 16 steps + 1 chunk x 15 steps = 255
    int base = 0;
    for (int k = 0; k < 16; ++k) {
        const int steps = (k < 15) ? 16 : 15;
        const float* uc = (k == 0) ? u0 : out + (size_t)(base - 1) * GNN;
        const float* up = (k == 0) ? u0 : out + (size_t)(base - 2) * GNN;
        wave_chunk<<<dim3(256), dim3(NTHR), 0, stream>>>(uc, up, alpha, out, base, steps);
        base += steps;
    }
}

// Round 2
// 364.016 us; speedup vs baseline: 1.1054x; 1.1054x over previous
//
#include <hip/hip_runtime.h>

#define GN      512
#define GNN     (GN * GN)
#define TILE    32
#define HALO    16          // halo radius = max steps per chunk
#define NTHR    1024
#define SURF    (17 * 64)   // one exchange surface: 16 slab rows + 1 zero pad row

// lane i <- lane i-1 (wave_shl:1), lane 0 <- 0. Pure VALU, no LDS.
__device__ __forceinline__ float dpp_left(float x) {
    return __int_as_float(__builtin_amdgcn_update_dpp(
        0, __float_as_int(x), 0x130, 0xF, 0xF, true));
}
// lane i <- lane i+1 (wave_shr:1), lane 63 <- 0.
__device__ __forceinline__ float dpp_right(float x) {
    return __int_as_float(__builtin_amdgcn_update_dpp(
        0, __float_as_int(x), 0x138, 0xF, 0xF, true));
}

// Temporal-blocked chunk, slab-ownership layout.
// Wave w owns rows 4w..4w+3 of the 64x64 region; lane l owns column l.
// Each thread: 4 cells (one column segment) in registers. Vertical neighbors
// inside the slab are registers; horizontal neighbors are lane+-1 via DPP
// (zero LDS); only the slab boundary rows (cell 0 up / cell 3 down) go
// through LDS: 2 ds_read_b32 + 2 ds_write_b32 per thread per step, vs the
// previous layout's 56B/thread of LDS traffic. Surfaces are [17][64] floats:
// botP[w] = wave w-1's bottom row (botP[0] = zero pad), topP[w+1] = wave
// w+1's top row (topP[16] = zero pad). Lane l -> bank l%32: conflict-free.
// Trapezoid invariant unchanged: 32x32 output tile is >= HALO=16 from the
// region edge, nsteps <= 16, so edge garbage (DPP zero-fill) never reaches it.
__global__ __launch_bounds__(NTHR)
void wave_chunk(const float* __restrict__ ucur,   // u at chunk base
                const float* __restrict__ uprev,  // u at chunk base - 1
                const float* __restrict__ alpha,
                float* __restrict__ out,
                int slice0, int nsteps)
{
    __shared__ __align__(16) float surf[4 * SURF];
    float* const topA = surf;
    float* const botA = surf + SURF;
    float* const topB = surf + 2 * SURF;
    float* const botB = surf + 3 * SURF;

    const int tid = threadIdx.x;
    const int w   = tid >> 6;        // wave id 0..15 = slab index
    const int l   = tid & 63;        // lane = region column

    const int bx  = blockIdx.x & 15;
    const int by  = blockIdx.x >> 4;
    const int gi0 = by * TILE - HALO + 4 * w;   // global row of my cell 0
    const int gj  = bx * TILE - HALO + l;       // global col

    for (int k = tid; k < 4 * SURF; k += NTHR) surf[k] = 0.0f;

    const float DX = 10.0f / 511.0f;
    const float K  = (5e-5f * 5e-5f) / (DX * DX);   // DT2/DX2

    float amp[4], cxs[4], cys[4];
#pragma unroll
    for (int g = 0; g < 4; ++g) {
        amp[g] = alpha[g];
        cxs[g] = alpha[4 + g];
        cys[g] = alpha[8 + g];
    }
    const float Y = -5.0f + (float)gj * DX;
    float dy2[4];
#pragma unroll
    for (int g = 0; g < 4; ++g) { const float dy = Y - cys[g]; dy2[g] = dy * dy; }

    float kc2[4], bm[4], cur[4], prv[4];
    const bool colin = ((unsigned)gj < GN);
#pragma unroll
    for (int k = 0; k < 4; ++k) {
        const int gi = gi0 + k;
        const float X = -5.0f + (float)gi * DX;
        float cv = 2.0f;
#pragma unroll
        for (int g = 0; g < 4; ++g) {
            const float dx = X - cxs[g];
            cv += amp[g] * __expf(-(dx * dx + dy2[g]));
        }
        kc2[k] = K * (cv * cv);
        bm[k]  = (gi >= 1 && gi <= GN - 2 && gj >= 1 && gj <= GN - 2) ? 1.0f : 0.0f;
        const bool inb = colin && ((unsigned)gi < GN);
        const long off = (long)gi * GN + gj;
        cur[k] = inb ? ucur[off] : 0.0f;     // lanes coalesced: 64 consecutive floats/row
        prv[k] = inb ? uprev[off] : 0.0f;
    }

    const int sTop = (w << 6) + l;    // [w][l]   : my top-row slot / my up-source
    const int sBot = sTop + 64;       // [w+1][l] : my bottom-row slot / my dn-source

    __syncthreads();                  // zero-init done before population
    topA[sTop] = cur[0];
    botA[sBot] = cur[3];
    __syncthreads();

    const bool inTile = (w >= 4 && w < 12) && (l >= HALO) && (l < HALO + TILE);
    float* op = out + ((long)slice0 * GNN + (long)gi0 * GN + gj);  // wild if !inTile; never deref'd

// One time step: reads surfaces (tRd,bRd), writes (tWr,bWr); new state lands in p
// (old prv regs are dead after use -> no register copies, roles swap per call).
// nw0/nw3 computed first so their 2 ds_writes drain under the cells-1/2 VALU.
// Barrier needs lgkmcnt only: global stores are consumed by the NEXT dispatch.
#define STEP(c, p, tRd, bRd, tWr, bWr)  do {                                          \
        const float up0 = bRd[sTop];                                                  \
        const float dn3 = tRd[sBot];                                                  \
        const float lr0 = dpp_left(c[0]) + dpp_right(c[0]);                           \
        const float lr3 = dpp_left(c[3]) + dpp_right(c[3]);                           \
        const float n0 = bm[0] * (2.0f*c[0] - p[0] + kc2[0]*(up0 + c[1] + lr0 - 4.0f*c[0])); \
        const float n3 = bm[3] * (2.0f*c[3] - p[3] + kc2[3]*(c[2] + dn3 + lr3 - 4.0f*c[3])); \
        tWr[sTop] = n0;                                                               \
        bWr[sBot] = n3;                                                               \
        const float lr1 = dpp_left(c[1]) + dpp_right(c[1]);                           \
        const float lr2 = dpp_left(c[2]) + dpp_right(c[2]);                           \
        const float n1 = bm[1] * (2.0f*c[1] - p[1] + kc2[1]*(c[0] + c[2] + lr1 - 4.0f*c[1])); \
        const float n2 = bm[2] * (2.0f*c[2] - p[2] + kc2[2]*(c[1] + c[3] + lr2 - 4.0f*c[2])); \
        p[0] = n0; p[1] = n1; p[2] = n2; p[3] = n3;                                   \
        if (inTile) { op[0] = n0; op[GN] = n1; op[2*GN] = n2; op[3*GN] = n3; }        \
        op += GNN;                                                                    \
        asm volatile("s_waitcnt lgkmcnt(0)" ::: "memory");                            \
        __builtin_amdgcn_s_barrier();                                                 \
    } while (0)

    int s = 0;
    for (; s + 2 <= nsteps; s += 2) {
        STEP(cur, prv, topA, botA, topB, botB);   // even step: read A, write B
        STEP(prv, cur, topB, botB, topA, botA);   // odd step:  read B, write A
    }
    if (s < nsteps) {                             // nsteps=15 tail (step 14, reads A)
        STEP(cur, prv, topA, botA, topB, botB);
    }
#undef STEP
}

extern "C" void kernel_launch(void* const* d_in, const int* in_sizes, int n_in,
                              void* d_out, int out_size, void* d_ws, size_t ws_size,
                              hipStream_t stream)
{
    const float* u0    = (const float*)d_in[0];
    const float* alpha = (const float*)d_in[1];
    float*       out   = (float*)d_out;

    // 15 chunks x 16 steps + 1 chunk x 15 steps = 255
    int base = 0;
    for (int k = 0; k < 16; ++k) {
        const int steps = (k < 15) ? 16 : 15;
        const float* uc = (k == 0) ? u0 : out + (size_t)(base - 1) * GNN;
        const float* up = (k == 0) ? u0 : out + (size_t)(base - 2) * GNN;
        wave_chunk<<<dim3(256), dim3(NTHR), 0, stream>>>(uc, up, alpha, out, base, steps);
        base += steps;
    }
}